// Round 1
// baseline (703.053 us; speedup 1.0000x reference)
//
#include <hip/hip_runtime.h>
#include <stdint.h>

#define C 128
#define ALPHA_F 0.1f
#define ONE_MINUS_ALPHA 0.9f
// beta = log(THETA/LAYER + 1) = log(1.25)
#define BETA_F 0.22314355131420976f
#define ONE_MINUS_BETA 0.7768564486857902f

__global__ void k_deg_init(float* __restrict__ deg, int n) {
    int i = blockIdx.x * blockDim.x + threadIdx.x;
    if (i < n) deg[i] = 1.0f;  // self-loop
}

__global__ void k_deg_count(const int* __restrict__ dst, float* __restrict__ deg, int e) {
    int i = blockIdx.x * blockDim.x + threadIdx.x;
    if (i < e) atomicAdd(&deg[dst[i]], 1.0f);
}

__global__ void k_dinv(const float* __restrict__ deg, float* __restrict__ dinv, int n) {
    int i = blockIdx.x * blockDim.x + threadIdx.x;
    if (i < n) dinv[i] = rsqrtf(deg[i]);
}

// prop[i][:] = x[i][:] * (1/deg[i])   (self-loop term: dinv[i]*dinv[i] = 1/deg[i])
__global__ void k_prop_init(const float* __restrict__ x, const float* __restrict__ deg,
                            float* __restrict__ prop, int n) {
    int t = blockIdx.x * blockDim.x + threadIdx.x;
    int total = n * (C / 4);
    if (t < total) {
        int i = t >> 5;  // t / (C/4)
        float inv = 1.0f / deg[i];
        float4 v = ((const float4*)x)[t];
        v.x *= inv; v.y *= inv; v.z *= inv; v.w *= inv;
        ((float4*)prop)[t] = v;
    }
}

// One wave per edge; lane handles 2 channels (float2 load, 2 f32 atomics).
__global__ void k_scatter(const float* __restrict__ x, const int* __restrict__ src,
                          const int* __restrict__ dst, const float* __restrict__ dinv,
                          float* __restrict__ prop, int e) {
    int lane = threadIdx.x & 63;
    int w = threadIdx.x >> 6;           // 4 waves per 256-thread block
    int step = gridDim.x * 4;
    for (int i = blockIdx.x * 4 + w; i < e; i += step) {
        int s = src[i];
        int d = dst[i];
        float norm = dinv[s] * dinv[d];
        float2 v = ((const float2*)(x + (size_t)s * C))[lane];
        float* p = prop + (size_t)d * C + lane * 2;
        atomicAdd(p,     v.x * norm);
        atomicAdd(p + 1, v.y * norm);
    }
}

// Fused: s = 0.9*prop + 0.1*x0 ; out = (1-beta)*s + beta*(s @ W^T + b)
// Block: 256 threads, tile 64 rows x 128 cols. W^T staged in LDS (pad 132),
// s-tile transposed in LDS (pad 68). Register blocking 8 rows x 4 cols.
__global__ __launch_bounds__(256)
void k_out(const float* __restrict__ prop, const float* __restrict__ x0,
           const float* __restrict__ W, const float* __restrict__ bias,
           float* __restrict__ out, int n) {
    __shared__ float Wt[C][132];  // Wt[c][j] = W[j][c]; pad 132 keeps float4 reads 16B-aligned
    __shared__ float st[C][68];   // st[c][r] = s[row0+r][c]; pad 68 (16B-aligned b128 reads)

    int tid = threadIdx.x;

    // Stage W transposed: coalesced global read, conflict-spread LDS write.
    for (int idx = tid; idx < C * C; idx += 256) {
        int j = idx >> 7;
        int c = idx & 127;
        Wt[c][j] = W[idx];
    }

    int row0 = blockIdx.x * 64;

    // Stage s-tile transposed (64 rows). Coalesced float4 global reads.
    for (int idx = tid; idx < 64 * (C / 4); idx += 256) {
        int r  = idx >> 5;       // 0..63
        int cq = idx & 31;       // float4 column
        int grow = row0 + r;
        float4 sv = make_float4(0.f, 0.f, 0.f, 0.f);
        if (grow < n) {
            float4 p4 = ((const float4*)(prop + (size_t)grow * C))[cq];
            float4 x4 = ((const float4*)(x0   + (size_t)grow * C))[cq];
            sv.x = ONE_MINUS_ALPHA * p4.x + ALPHA_F * x4.x;
            sv.y = ONE_MINUS_ALPHA * p4.y + ALPHA_F * x4.y;
            sv.z = ONE_MINUS_ALPHA * p4.z + ALPHA_F * x4.z;
            sv.w = ONE_MINUS_ALPHA * p4.w + ALPHA_F * x4.w;
        }
        st[4 * cq + 0][r] = sv.x;
        st[4 * cq + 1][r] = sv.y;
        st[4 * cq + 2][r] = sv.z;
        st[4 * cq + 3][r] = sv.w;
    }
    __syncthreads();

    int tc = tid & 31;   // j = 4*tc + jj
    int tr = tid >> 5;   // r = 8*tr + rr
    float acc[8][4];
    #pragma unroll
    for (int rr = 0; rr < 8; ++rr)
        #pragma unroll
        for (int jj = 0; jj < 4; ++jj) acc[rr][jj] = 0.f;

    #pragma unroll 2
    for (int c = 0; c < C; ++c) {
        float4 wv = *(const float4*)&Wt[c][4 * tc];
        float4 sa = *(const float4*)&st[c][8 * tr];
        float4 sb = *(const float4*)&st[c][8 * tr + 4];
        float sv[8] = {sa.x, sa.y, sa.z, sa.w, sb.x, sb.y, sb.z, sb.w};
        #pragma unroll
        for (int rr = 0; rr < 8; ++rr) {
            acc[rr][0] += sv[rr] * wv.x;
            acc[rr][1] += sv[rr] * wv.y;
            acc[rr][2] += sv[rr] * wv.z;
            acc[rr][3] += sv[rr] * wv.w;
        }
    }

    float4 b4 = ((const float4*)bias)[tc];
    float bb[4] = {b4.x, b4.y, b4.z, b4.w};
    #pragma unroll
    for (int rr = 0; rr < 8; ++rr) {
        int r = 8 * tr + rr;
        int grow = row0 + r;
        if (grow < n) {
            float4 o;
            float s0 = st[4 * tc + 0][r];
            float s1 = st[4 * tc + 1][r];
            float s2 = st[4 * tc + 2][r];
            float s3 = st[4 * tc + 3][r];
            o.x = ONE_MINUS_BETA * s0 + BETA_F * (acc[rr][0] + bb[0]);
            o.y = ONE_MINUS_BETA * s1 + BETA_F * (acc[rr][1] + bb[1]);
            o.z = ONE_MINUS_BETA * s2 + BETA_F * (acc[rr][2] + bb[2]);
            o.w = ONE_MINUS_BETA * s3 + BETA_F * (acc[rr][3] + bb[3]);
            ((float4*)(out + (size_t)grow * C))[tc] = o;
        }
    }
}

extern "C" void kernel_launch(void* const* d_in, const int* in_sizes, int n_in,
                              void* d_out, int out_size, void* d_ws, size_t ws_size,
                              hipStream_t stream) {
    const float* x   = (const float*)d_in[0];
    const float* x0  = (const float*)d_in[1];
    const float* W   = (const float*)d_in[2];
    const float* b   = (const float*)d_in[3];
    const int*   ei  = (const int*)d_in[4];

    int n = in_sizes[0] / C;
    int e = in_sizes[4] / 2;
    const int* src = ei;
    const int* dst = ei + e;

    float* deg  = (float*)d_ws;
    float* dinv = deg + n;
    float* prop = (float*)((((uintptr_t)(dinv + n)) + 15) & ~(uintptr_t)15);
    float* out  = (float*)d_out;

    k_deg_init <<<(n + 255) / 256, 256, 0, stream>>>(deg, n);
    k_deg_count<<<(e + 255) / 256, 256, 0, stream>>>(dst, deg, e);
    k_dinv     <<<(n + 255) / 256, 256, 0, stream>>>(deg, dinv, n);
    k_prop_init<<<(n * (C / 4) + 255) / 256, 256, 0, stream>>>(x, deg, prop, n);
    k_scatter  <<<8192, 256, 0, stream>>>(x, src, dst, dinv, prop, e);
    k_out      <<<(n + 63) / 64, 256, 0, stream>>>(prop, x0, W, b, out, n);
}

// Round 2
// 252.536 us; speedup vs baseline: 2.7840x; 2.7840x over previous
//
#include <hip/hip_runtime.h>
#include <stdint.h>

#define C 128
#define ALPHA_F 0.1f
#define ONE_MINUS_ALPHA 0.9f
// beta = log(THETA/LAYER + 1) = log(1.25)
#define BETA_F 0.22314355131420976f
#define ONE_MINUS_BETA 0.7768564486857902f

// ---------------- counting sort of edges by destination ----------------

__global__ void k_zero(int* __restrict__ cnt, int n) {
    int i = blockIdx.x * blockDim.x + threadIdx.x;
    if (i < n) cnt[i] = 0;
}

__global__ void k_hist(const int* __restrict__ dst, int* __restrict__ cnt, int e) {
    int i = blockIdx.x * blockDim.x + threadIdx.x;
    if (i < e) atomicAdd(&cnt[dst[i]], 1);
}

// block sums of cnt -> part[]
__global__ __launch_bounds__(256)
void k_scan_a(const int* __restrict__ cnt, int* __restrict__ part, int n) {
    __shared__ int s[256];
    int t = threadIdx.x;
    int i = blockIdx.x * 256 + t;
    s[t] = (i < n) ? cnt[i] : 0;
    __syncthreads();
    for (int off = 128; off > 0; off >>= 1) {
        if (t < off) s[t] += s[t + off];
        __syncthreads();
    }
    if (t == 0) part[blockIdx.x] = s[0];
}

// exclusive scan of part[np] in a single 512-thread block (np <= 512)
__global__ __launch_bounds__(512)
void k_scan_b(int* __restrict__ part, int np) {
    __shared__ int a[512];
    __shared__ int b[512];
    int t = threadIdx.x;
    a[t] = (t < np) ? part[t] : 0;
    __syncthreads();
    int* cur = a;
    int* nxt = b;
    for (int off = 1; off < 512; off <<= 1) {
        nxt[t] = cur[t] + ((t >= off) ? cur[t - off] : 0);
        __syncthreads();
        int* tmp = cur; cur = nxt; nxt = tmp;
    }
    if (t < np) part[t] = (t > 0) ? cur[t - 1] : 0;  // exclusive
}

// per-element exclusive scan within block + part offset -> row_ptr, cursor, dinv
__global__ __launch_bounds__(256)
void k_scan_c(const int* __restrict__ cnt, const int* __restrict__ part,
              int* __restrict__ row_ptr, int* __restrict__ cursor,
              float* __restrict__ dinv, int n) {
    __shared__ int a[256];
    __shared__ int b[256];
    int t = threadIdx.x;
    int i = blockIdx.x * 256 + t;
    int v = (i < n) ? cnt[i] : 0;
    a[t] = v;
    __syncthreads();
    int* cur = a;
    int* nxt = b;
    for (int off = 1; off < 256; off <<= 1) {
        nxt[t] = cur[t] + ((t >= off) ? cur[t - off] : 0);
        __syncthreads();
        int* tmp = cur; cur = nxt; nxt = tmp;
    }
    if (i < n) {
        int rp = part[blockIdx.x] + cur[t] - v;   // exclusive prefix
        row_ptr[i] = rp;
        cursor[i]  = rp;
        dinv[i]    = rsqrtf((float)(v + 1));      // deg includes self-loop
    }
}

__global__ void k_place(const int* __restrict__ src, const int* __restrict__ dst,
                        int* __restrict__ cursor, int* __restrict__ sorted_src, int e) {
    int i = blockIdx.x * blockDim.x + threadIdx.x;
    if (i < e) {
        int d = dst[i];
        int pos = atomicAdd(&cursor[d], 1);
        sorted_src[pos] = src[i];
    }
}

// ---------------- gather + alpha-blend -> sout (= d_out) ----------------
// One wave per destination node; lane holds channels [2*lane, 2*lane+1].
__global__ __launch_bounds__(256)
void k_gather(const float* __restrict__ x, const float* __restrict__ x0,
              const int* __restrict__ sorted_src, const int* __restrict__ row_ptr,
              const int* __restrict__ cnt, const float* __restrict__ dinv,
              float* __restrict__ sout, int n) {
    int lane = threadIdx.x & 63;
    int idx = blockIdx.x * 4 + (threadIdx.x >> 6);
    if (idx >= n) return;

    const float2* x2 = (const float2*)x;
    float dv = dinv[idx];

    float2 acc = x2[(size_t)idx * 64 + lane];
    float selfn = dv * dv;                     // dinv[i]^2 = 1/deg[i]
    acc.x *= selfn; acc.y *= selfn;

    int start = row_ptr[idx];
    int len   = cnt[idx];

    int j = 0;
    for (; j + 2 <= len; j += 2) {
        int s0 = sorted_src[start + j];
        int s1 = sorted_src[start + j + 1];
        float n0 = dinv[s0] * dv;
        float n1 = dinv[s1] * dv;
        float2 v0 = x2[(size_t)s0 * 64 + lane];
        float2 v1 = x2[(size_t)s1 * 64 + lane];
        acc.x += v0.x * n0 + v1.x * n1;
        acc.y += v0.y * n0 + v1.y * n1;
    }
    if (j < len) {
        int s0 = sorted_src[start + j];
        float n0 = dinv[s0] * dv;
        float2 v0 = x2[(size_t)s0 * 64 + lane];
        acc.x += v0.x * n0;
        acc.y += v0.y * n0;
    }

    float2 xv = ((const float2*)x0)[(size_t)idx * 64 + lane];
    float2 o;
    o.x = ONE_MINUS_ALPHA * acc.x + ALPHA_F * xv.x;
    o.y = ONE_MINUS_ALPHA * acc.y + ALPHA_F * xv.y;
    ((float2*)sout)[(size_t)idx * 64 + lane] = o;
}

// ---------------- fused epilogue GEMM ----------------
// out = (1-beta)*s + beta*(s @ W^T + b), s read from sout (== out buffer; each
// block reads its own 64 rows into LDS before overwriting them).
__global__ __launch_bounds__(256)
void k_out(const float* __restrict__ sin, const float* __restrict__ W,
           const float* __restrict__ bias, float* __restrict__ out, int n) {
    __shared__ float Wt[C][132];  // Wt[c][j] = W[j][c]
    __shared__ float st[C][68];   // st[c][r] = s[row0+r][c]

    int tid = threadIdx.x;

    for (int idx = tid; idx < C * C; idx += 256) {
        int j = idx >> 7;
        int c = idx & 127;
        Wt[c][j] = W[idx];
    }

    int row0 = blockIdx.x * 64;

    for (int idx = tid; idx < 64 * (C / 4); idx += 256) {
        int r  = idx >> 5;
        int cq = idx & 31;
        int grow = row0 + r;
        float4 sv = make_float4(0.f, 0.f, 0.f, 0.f);
        if (grow < n) {
            sv = ((const float4*)(sin + (size_t)grow * C))[cq];
        }
        st[4 * cq + 0][r] = sv.x;
        st[4 * cq + 1][r] = sv.y;
        st[4 * cq + 2][r] = sv.z;
        st[4 * cq + 3][r] = sv.w;
    }
    __syncthreads();

    int tc = tid & 31;
    int tr = tid >> 5;
    float acc[8][4];
    #pragma unroll
    for (int rr = 0; rr < 8; ++rr)
        #pragma unroll
        for (int jj = 0; jj < 4; ++jj) acc[rr][jj] = 0.f;

    #pragma unroll 2
    for (int c = 0; c < C; ++c) {
        float4 wv = *(const float4*)&Wt[c][4 * tc];
        float4 sa = *(const float4*)&st[c][8 * tr];
        float4 sb = *(const float4*)&st[c][8 * tr + 4];
        float sv[8] = {sa.x, sa.y, sa.z, sa.w, sb.x, sb.y, sb.z, sb.w};
        #pragma unroll
        for (int rr = 0; rr < 8; ++rr) {
            acc[rr][0] += sv[rr] * wv.x;
            acc[rr][1] += sv[rr] * wv.y;
            acc[rr][2] += sv[rr] * wv.z;
            acc[rr][3] += sv[rr] * wv.w;
        }
    }

    float4 b4 = ((const float4*)bias)[tc];
    float bb[4] = {b4.x, b4.y, b4.z, b4.w};
    #pragma unroll
    for (int rr = 0; rr < 8; ++rr) {
        int r = 8 * tr + rr;
        int grow = row0 + r;
        if (grow < n) {
            float4 o;
            float s0 = st[4 * tc + 0][r];
            float s1 = st[4 * tc + 1][r];
            float s2 = st[4 * tc + 2][r];
            float s3 = st[4 * tc + 3][r];
            o.x = ONE_MINUS_BETA * s0 + BETA_F * (acc[rr][0] + bb[0]);
            o.y = ONE_MINUS_BETA * s1 + BETA_F * (acc[rr][1] + bb[1]);
            o.z = ONE_MINUS_BETA * s2 + BETA_F * (acc[rr][2] + bb[2]);
            o.w = ONE_MINUS_BETA * s3 + BETA_F * (acc[rr][3] + bb[3]);
            ((float4*)(out + (size_t)grow * C))[tc] = o;
        }
    }
}

extern "C" void kernel_launch(void* const* d_in, const int* in_sizes, int n_in,
                              void* d_out, int out_size, void* d_ws, size_t ws_size,
                              hipStream_t stream) {
    const float* x   = (const float*)d_in[0];
    const float* x0  = (const float*)d_in[1];
    const float* W   = (const float*)d_in[2];
    const float* b   = (const float*)d_in[3];
    const int*   ei  = (const int*)d_in[4];

    int n = in_sizes[0] / C;
    int e = in_sizes[4] / 2;
    const int* src = ei;
    const int* dst = ei + e;

    int*   cnt        = (int*)d_ws;
    int*   row_ptr    = cnt + n;
    int*   cursor     = row_ptr + n;
    float* dinv       = (float*)(cursor + n);
    int*   part       = (int*)(dinv + n);          // scan partials (<=512)
    int*   sorted_src = part + 512;

    float* sout = (float*)d_out;

    int nb  = (n + 255) / 256;   // 391 blocks, <= 512 partials
    int eb  = (e + 255) / 256;

    k_zero  <<<nb, 256, 0, stream>>>(cnt, n);
    k_hist  <<<eb, 256, 0, stream>>>(dst, cnt, e);
    k_scan_a<<<nb, 256, 0, stream>>>(cnt, part, n);
    k_scan_b<<<1, 512, 0, stream>>>(part, nb);
    k_scan_c<<<nb, 256, 0, stream>>>(cnt, part, row_ptr, cursor, dinv, n);
    k_place <<<eb, 256, 0, stream>>>(src, dst, cursor, sorted_src, e);
    k_gather<<<(n + 3) / 4, 256, 0, stream>>>(x, x0, sorted_src, row_ptr, cnt, dinv, sout, n);
    k_out   <<<(n + 63) / 64, 256, 0, stream>>>(sout, W, b, sout, n);
}

// Round 3
// 207.253 us; speedup vs baseline: 3.3922x; 1.2185x over previous
//
#include <hip/hip_runtime.h>
#include <stdint.h>

#define C 128
#define ALPHA_F 0.1f
#define ONE_MINUS_ALPHA 0.9f
// beta = log(THETA/LAYER + 1) = log(1.25)
#define BETA_F 0.22314355131420976f
#define ONE_MINUS_BETA 0.7768564486857902f

// ---------------- counting sort of edges by destination ----------------

__global__ void k_zero(int* __restrict__ cnt, int n) {
    int i = blockIdx.x * blockDim.x + threadIdx.x;
    if (i < n) cnt[i] = 0;
}

__global__ void k_hist(const int* __restrict__ dst, int* __restrict__ cnt, int e) {
    int i = blockIdx.x * blockDim.x + threadIdx.x;
    if (i < e) atomicAdd(&cnt[dst[i]], 1);
}

__global__ __launch_bounds__(256)
void k_scan_a(const int* __restrict__ cnt, int* __restrict__ part, int n) {
    __shared__ int s[256];
    int t = threadIdx.x;
    int i = blockIdx.x * 256 + t;
    s[t] = (i < n) ? cnt[i] : 0;
    __syncthreads();
    for (int off = 128; off > 0; off >>= 1) {
        if (t < off) s[t] += s[t + off];
        __syncthreads();
    }
    if (t == 0) part[blockIdx.x] = s[0];
}

__global__ __launch_bounds__(512)
void k_scan_b(int* __restrict__ part, int np) {
    __shared__ int a[512];
    __shared__ int b[512];
    int t = threadIdx.x;
    a[t] = (t < np) ? part[t] : 0;
    __syncthreads();
    int* cur = a;
    int* nxt = b;
    for (int off = 1; off < 512; off <<= 1) {
        nxt[t] = cur[t] + ((t >= off) ? cur[t - off] : 0);
        __syncthreads();
        int* tmp = cur; cur = nxt; nxt = tmp;
    }
    if (t < np) part[t] = (t > 0) ? cur[t - 1] : 0;  // exclusive
}

__global__ __launch_bounds__(256)
void k_scan_c(const int* __restrict__ cnt, const int* __restrict__ part,
              int* __restrict__ row_ptr, int* __restrict__ cursor,
              float* __restrict__ dinv, int n) {
    __shared__ int a[256];
    __shared__ int b[256];
    int t = threadIdx.x;
    int i = blockIdx.x * 256 + t;
    int v = (i < n) ? cnt[i] : 0;
    a[t] = v;
    __syncthreads();
    int* cur = a;
    int* nxt = b;
    for (int off = 1; off < 256; off <<= 1) {
        nxt[t] = cur[t] + ((t >= off) ? cur[t - off] : 0);
        __syncthreads();
        int* tmp = cur; cur = nxt; nxt = tmp;
    }
    if (i < n) {
        int rp = part[blockIdx.x] + cur[t] - v;
        row_ptr[i] = rp;
        cursor[i]  = rp;
        dinv[i]    = rsqrtf((float)(v + 1));  // deg includes self-loop
    }
}

__global__ void k_place(const int* __restrict__ src, const int* __restrict__ dst,
                        int* __restrict__ cursor, int* __restrict__ sorted_src, int e) {
    int i = blockIdx.x * blockDim.x + threadIdx.x;
    if (i < e) {
        int d = dst[i];
        int pos = atomicAdd(&cursor[d], 1);
        sorted_src[pos] = src[i];
    }
}

// W transpose: Wt[c][j] = W[j][c]
__global__ void k_wt(const float* __restrict__ W, float* __restrict__ Wt) {
    int i = blockIdx.x * 256 + threadIdx.x;
    if (i < C * C) {
        int j = i >> 7;
        int c = i & 127;
        Wt[c * C + j] = W[i];
    }
}

// ---------------- gather + alpha-blend -> sout (= d_out) ----------------
// One wave per destination node. Half-waves process even/odd edges (32 lanes
// x float4 = full 128-ch row each); merged at the end via shfl_xor(32).
__global__ __launch_bounds__(256)
void k_gather(const float* __restrict__ x, const float* __restrict__ x0,
              const int* __restrict__ sorted_src, const int* __restrict__ row_ptr,
              const int* __restrict__ cnt, const float* __restrict__ dinv,
              float* __restrict__ sout, int n) {
    int half = (threadIdx.x >> 5) & 1;   // even/odd edge stream
    int l32  = threadIdx.x & 31;         // float4 channel group
    int idx  = blockIdx.x * 4 + (threadIdx.x >> 6);
    if (idx >= n) return;

    const float4* x4 = (const float4*)x;
    float dv = dinv[idx];
    int start = row_ptr[idx];
    int len   = cnt[idx];

    float4 acc = make_float4(0.f, 0.f, 0.f, 0.f);

    int j = half;
    for (; j + 2 < len; j += 4) {  // two edges per iteration for this half
        int s0 = sorted_src[start + j];
        int s1 = sorted_src[start + j + 2];
        float n0 = dinv[s0] * dv;
        float n1 = dinv[s1] * dv;
        float4 v0 = x4[(size_t)s0 * 32 + l32];
        float4 v1 = x4[(size_t)s1 * 32 + l32];
        acc.x += v0.x * n0 + v1.x * n1;
        acc.y += v0.y * n0 + v1.y * n1;
        acc.z += v0.z * n0 + v1.z * n1;
        acc.w += v0.w * n0 + v1.w * n1;
    }
    if (j < len) {
        int s0 = sorted_src[start + j];
        float n0 = dinv[s0] * dv;
        float4 v0 = x4[(size_t)s0 * 32 + l32];
        acc.x += v0.x * n0;
        acc.y += v0.y * n0;
        acc.z += v0.z * n0;
        acc.w += v0.w * n0;
    }

    // merge even/odd halves (lanes l and l^32 hold the same channels)
    acc.x += __shfl_xor(acc.x, 32, 64);
    acc.y += __shfl_xor(acc.y, 32, 64);
    acc.z += __shfl_xor(acc.z, 32, 64);
    acc.w += __shfl_xor(acc.w, 32, 64);

    if (half == 0) {
        float selfn = dv * dv;  // 1/deg
        float4 sv = x4[(size_t)idx * 32 + l32];
        float4 xv = ((const float4*)x0)[(size_t)idx * 32 + l32];
        float4 o;
        o.x = ONE_MINUS_ALPHA * (acc.x + sv.x * selfn) + ALPHA_F * xv.x;
        o.y = ONE_MINUS_ALPHA * (acc.y + sv.y * selfn) + ALPHA_F * xv.y;
        o.z = ONE_MINUS_ALPHA * (acc.z + sv.z * selfn) + ALPHA_F * xv.z;
        o.w = ONE_MINUS_ALPHA * (acc.w + sv.w * selfn) + ALPHA_F * xv.w;
        ((float4*)sout)[(size_t)idx * 32 + l32] = o;
    }
}

// ---------------- fused epilogue GEMM ----------------
// out = (1-beta)*s + beta*(s @ W^T + b). s-tile (64 rows) staged row-major in
// LDS (33.8 KB -> 4 blocks/CU); Wt read from global (64 KB, L1/L2-resident).
__global__ __launch_bounds__(256)
void k_out(const float* __restrict__ sin, const float* __restrict__ Wt,
           const float* __restrict__ bias, float* __restrict__ out, int n) {
    __shared__ float st[64][132];   // row-major s tile; b128 conflict-free

    int tid = threadIdx.x;
    int row0 = blockIdx.x * 64;

    for (int idx = tid; idx < 64 * 32; idx += 256) {
        int r  = idx >> 5;
        int cq = idx & 31;
        int grow = row0 + r;
        float4 sv = make_float4(0.f, 0.f, 0.f, 0.f);
        if (grow < n) sv = ((const float4*)(sin + (size_t)grow * C))[cq];
        *(float4*)&st[r][4 * cq] = sv;
    }
    __syncthreads();

    int tc = tid & 31;   // output float4 column group: j = 4*tc + jj
    int tr = tid >> 5;   // rows 8*tr .. 8*tr+7
    const float4* Wt4 = (const float4*)Wt;

    float acc[8][4];
    #pragma unroll
    for (int rr = 0; rr < 8; ++rr)
        #pragma unroll
        for (int jj = 0; jj < 4; ++jj) acc[rr][jj] = 0.f;

    #pragma unroll 2
    for (int c = 0; c < C; c += 4) {
        float4 w0 = Wt4[(size_t)(c + 0) * 32 + tc];
        float4 w1 = Wt4[(size_t)(c + 1) * 32 + tc];
        float4 w2 = Wt4[(size_t)(c + 2) * 32 + tc];
        float4 w3 = Wt4[(size_t)(c + 3) * 32 + tc];
        #pragma unroll
        for (int rr = 0; rr < 8; ++rr) {
            float4 sr = *(const float4*)&st[8 * tr + rr][c];
            acc[rr][0] += sr.x * w0.x + sr.y * w1.x + sr.z * w2.x + sr.w * w3.x;
            acc[rr][1] += sr.x * w0.y + sr.y * w1.y + sr.z * w2.y + sr.w * w3.y;
            acc[rr][2] += sr.x * w0.z + sr.y * w1.z + sr.z * w2.z + sr.w * w3.z;
            acc[rr][3] += sr.x * w0.w + sr.y * w1.w + sr.z * w2.w + sr.w * w3.w;
        }
    }

    float4 b4 = ((const float4*)bias)[tc];
    #pragma unroll
    for (int rr = 0; rr < 8; ++rr) {
        int r = 8 * tr + rr;
        int grow = row0 + r;
        if (grow < n) {
            float4 sv = *(const float4*)&st[r][4 * tc];
            float4 o;
            o.x = ONE_MINUS_BETA * sv.x + BETA_F * (acc[rr][0] + b4.x);
            o.y = ONE_MINUS_BETA * sv.y + BETA_F * (acc[rr][1] + b4.y);
            o.z = ONE_MINUS_BETA * sv.z + BETA_F * (acc[rr][2] + b4.z);
            o.w = ONE_MINUS_BETA * sv.w + BETA_F * (acc[rr][3] + b4.w);
            ((float4*)(out + (size_t)grow * C))[tc] = o;
        }
    }
}

extern "C" void kernel_launch(void* const* d_in, const int* in_sizes, int n_in,
                              void* d_out, int out_size, void* d_ws, size_t ws_size,
                              hipStream_t stream) {
    const float* x   = (const float*)d_in[0];
    const float* x0  = (const float*)d_in[1];
    const float* W   = (const float*)d_in[2];
    const float* b   = (const float*)d_in[3];
    const int*   ei  = (const int*)d_in[4];

    int n = in_sizes[0] / C;
    int e = in_sizes[4] / 2;
    const int* src = ei;
    const int* dst = ei + e;

    int*   cnt        = (int*)d_ws;
    int*   row_ptr    = cnt + n;
    int*   cursor     = row_ptr + n;
    float* dinv       = (float*)(cursor + n);
    int*   part       = (int*)(dinv + n);
    int*   sorted_src = part + 512;
    float* Wt         = (float*)(sorted_src + e);

    float* sout = (float*)d_out;

    int nb = (n + 255) / 256;
    int eb = (e + 255) / 256;

    k_zero  <<<nb, 256, 0, stream>>>(cnt, n);
    k_hist  <<<eb, 256, 0, stream>>>(dst, cnt, e);
    k_wt    <<<(C * C + 255) / 256, 256, 0, stream>>>(W, Wt);
    k_scan_a<<<nb, 256, 0, stream>>>(cnt, part, n);
    k_scan_b<<<1, 512, 0, stream>>>(part, nb);
    k_scan_c<<<nb, 256, 0, stream>>>(cnt, part, row_ptr, cursor, dinv, n);
    k_place <<<eb, 256, 0, stream>>>(src, dst, cursor, sorted_src, e);
    k_gather<<<(n + 3) / 4, 256, 0, stream>>>(x, x0, sorted_src, row_ptr, cnt, dinv, sout, n);
    k_out   <<<(n + 63) / 64, 256, 0, stream>>>(sout, Wt, b, sout, n);
}